// Round 10
// baseline (1083.359 us; speedup 1.0000x reference)
//
#include <hip/hip_runtime.h>
#include <cstdint>

// B=16, C=64, H=W=256. 3x3 convs via bf16 MFMA implicit GEMM.
// Round 10: weights-in-LDS (A-frags via ds_read -> compute has ZERO vmcnt
// consumers, staging floats across compute on the separate lgkmcnt/vmcnt
// counters), 512-thread 2-row blocks, dynamic LDS 142336B, depthwise+gate
// fused back into conv3 (f2 bf16 NCHW -> coalesced taps), k_fin deleted.
using short8  = __attribute__((ext_vector_type(8))) short;
using short4v = __attribute__((ext_vector_type(4))) short;
using f32x16  = __attribute__((ext_vector_type(16))) float;
using float4v = __attribute__((ext_vector_type(4))) float;
typedef unsigned short ushort_t;

#define CROW 520          // slots per staged row (65 mg x 8 slots, 16 ci)
#define CSLOTS 2080       // 4 rows per chunk
#define BSLOTS 2144       // padded (stage stripes overrun to 2139)
#define BSH (BSLOTS * 8)  // shorts per pixel buffer = 17152
#define WSH 36864         // weight shorts (72 frag-rows x 512)
#define DYN_LDS ((WSH + 2 * BSH) * 2)  // 142336 bytes

__device__ __forceinline__ float lrelu(float x) { return x > 0.f ? x : 0.1f * x; }

__device__ __forceinline__ ushort_t f2bf(float f) {
    union { float f; unsigned u; } v; v.f = f;
    unsigned r = (v.u + 0x7FFFu + ((v.u >> 16) & 1u)) >> 16;
    return (ushort_t)r;
}
__device__ __forceinline__ float bf2f(ushort_t b) {
    union { unsigned u; float f; } v; v.u = ((unsigned)b) << 16; return v.f;
}

// async 16B global -> LDS (dest = wave-uniform base + lane*16)
__device__ __forceinline__ void gload_lds16(const ushort_t* g, ushort_t* l) {
    __builtin_amdgcn_global_load_lds(
        (const __attribute__((address_space(1))) void*)g,
        (__attribute__((address_space(3))) void*)l, 16, 0, 0);
}

#define VMCNT(n) asm volatile("s_waitcnt vmcnt(" #n ")" ::: "memory")
#define RBAR() __builtin_amdgcn_s_barrier()
#define SCHED0() __builtin_amdgcn_sched_barrier(0)

// ---------------------------------------------------------------------------
// Tiny branch: ktr[b][tap][c] = leaky(kern) * sigmoid-gate (mv folded in).
// ---------------------------------------------------------------------------
__global__ void k_tiny(const float* __restrict__ t, const float* __restrict__ tW1,
                       const float* __restrict__ tW2, const float* __restrict__ kW1,
                       const float* __restrict__ kW2, float* __restrict__ ktr) {
    int b = blockIdx.x;
    int c = threadIdx.x;  // 64
    __shared__ float h1[64], g1[64];
    float ts = t[b];
    h1[c] = lrelu(ts * tW1[c]);
    g1[c] = lrelu(ts * kW1[c]);
    __syncthreads();
    float s = 0.f;
    for (int j = 0; j < 64; ++j) s = fmaf(tW2[c * 64 + j], h1[j], s);
    float mvv = 1.f / (1.f + expf(-s));
    for (int q = 0; q < 9; ++q) {
        float s2 = 0.f;
        for (int j = 0; j < 64; ++j) s2 = fmaf(kW2[(c * 9 + q) * 64 + j], g1[j], s2);
        ktr[b * 576 + q * 64 + c] = lrelu(s2) * mvv;
    }
}

// ---------------------------------------------------------------------------
// Zero row buffer (edge-redirect source for staging).
// ---------------------------------------------------------------------------
__global__ void k_zrow(ushort_t* __restrict__ z) {
    int i = blockIdx.x * 256 + threadIdx.x;  // 2048 threads, 16384 shorts
    *(short8*)(z + (size_t)i * 8) = (short8)0;
}

// ---------------------------------------------------------------------------
// Pack three 64x64x3x3 weight tensors into MFMA A-fragment order (bf16).
// flat = ((t*4 + chunk)*2 + ct)*512 + lane*8 + j
//   = W[co = ct*32 + (lane&31)][ci = chunk*16 + (lane>>5)*8 + j], tap t
// ---------------------------------------------------------------------------
__global__ void k_pack(const float* __restrict__ w1, const float* __restrict__ w2,
                       const float* __restrict__ w3, ushort_t* __restrict__ wp) {
    int idx = blockIdx.x * 256 + threadIdx.x;
    if (idx >= 3 * 36864) return;
    int conv = idx / 36864, r = idx % 36864;
    const float* W = conv == 0 ? w1 : (conv == 1 ? w2 : w3);
    int j = r & 7, lane = (r >> 3) & 63, ct = (r >> 9) & 1, chunk = (r >> 10) & 3,
        t = r >> 12;
    int co = ct * 32 + (lane & 31);
    int ci = chunk * 16 + (lane >> 5) * 8 + j;
    wp[idx] = f2bf(W[(co * 64 + ci) * 9 + t]);
}

// ---------------------------------------------------------------------------
// Transpose x: fp32 NCHW -> bf16 NHWC (width-256 rows). Block = (b,h).
// ---------------------------------------------------------------------------
__global__ __launch_bounds__(256) void k_tr(const float* __restrict__ x,
                                            ushort_t* __restrict__ xbf) {
    int bid = blockIdx.x;
    int h = bid & 255, b = bid >> 8;
    int t = threadIdx.x;
    for (int it = 0; it < 8; ++it) {
        int idx = t + it * 256;  // (w, g)
        int g = idx & 7, w = idx >> 3;
        const float* src = x + (((size_t)(b * 64 + g * 8) * 256 + h) * 256 + w);
        short8 v;
#pragma unroll
        for (int j = 0; j < 8; ++j) v[j] = (short)f2bf(src[(size_t)j * 65536]);
        *(short8*)(xbf + (((size_t)(b * 256 + h) * 256 + w) * 64 + g * 8)) = v;
    }
}

// ---------------------------------------------------------------------------
// Stage one 16-ci chunk: 4 rows x 258 pix, 5 x gload_lds16 per wave.
// Inverse swizzle baked into per-lane source address.
// ---------------------------------------------------------------------------
#define STAGE4(chunk, bufbase)                                                   \
    {                                                                            \
        _Pragma("unroll")                                                        \
        for (int i_ = 0; i_ < 5; ++i_) {                                         \
            int base_ = wv * 260 + i_ * 64;                                      \
            int S_ = base_ + lane;                                               \
            S_ = S_ < CSLOTS ? S_ : CSLOTS - 1;                                  \
            int r_ = (S_ >= 1560) ? 3 : ((S_ >= 1040) ? 2 : ((S_ >= 520) ? 1 : 0)); \
            int rem_ = S_ - r_ * 520;                                            \
            int mg_ = rem_ >> 3, sl_ = rem_ & 7;                                 \
            int sp_ = sl_ ^ (mg_ & 7);                                           \
            int p_ = mg_ * 4 + (sp_ >> 1), g_ = sp_ & 1;                         \
            int wsx_ = p_ - 1;                                                   \
            bool edge_ = (unsigned)wsx_ >= 256u;                                 \
            const ushort_t* rp_ =                                                \
                (r_ == 0) ? rb0 : ((r_ == 1) ? rb1 : ((r_ == 2) ? rb2 : rb3));   \
            const ushort_t* src_ =                                               \
                edge_ ? zv : (rp_ + wsx_ * 64 + (chunk)*16 + g_ * 8);            \
            gload_lds16(src_, xs + (bufbase) + (size_t)base_ * 8);               \
        }                                                                        \
    }

// ---------------------------------------------------------------------------
// Compute one 16-ci chunk: A (weights) and B (pixels) both from LDS.
// Pure lgkmcnt domain -> staging vmcnt ops float across this freely.
// ---------------------------------------------------------------------------
__device__ __forceinline__ void computeG(const ushort_t* __restrict__ wlds,
                                         const ushort_t* __restrict__ xs,
                                         int bufbase, int chunk, int lane, int pw0,
                                         int l31, int lhi, int rbase,
                                         f32x16 (&acc)[2][2]) {
    __builtin_amdgcn_s_setprio(1);
#pragma unroll
    for (int t = 0; t < 9; ++t) {
        const int off = ((t * 4 + chunk) * 2) * 512 + lane * 8;
        short8 a0 = *(const short8*)(wlds + off);
        short8 a1 = *(const short8*)(wlds + off + 512);
        const int dwx = t % 3, rr = t / 3;
        const int rowIdx = rbase + rr;
#pragma unroll
        for (int pt = 0; pt < 2; ++pt) {
            int p = pw0 + pt * 32 + l31 + dwx;
            int mg = p >> 2;
            int sl = ((p & 3) * 2 + lhi) ^ (mg & 7);
            short8 bf = *(const short8*)(
                xs + bufbase + (size_t)(rowIdx * 520 + mg * 8 + sl) * 8);
            acc[0][pt] = __builtin_amdgcn_mfma_f32_32x32x16_bf16(a0, bf, acc[0][pt], 0, 0, 0);
            acc[1][pt] = __builtin_amdgcn_mfma_f32_32x32x16_bf16(a1, bf, acc[1][pt], 0, 0, 0);
        }
    }
    __builtin_amdgcn_s_setprio(0);
}

// ---------------------------------------------------------------------------
// Generic 3x3 conv 64->64. Block = (b, h-pair) XCD-swizzled; 8 waves, each
// 64 c_out x 64 pix; weights preloaded to LDS. OMODE: 0 = bf16 NHWC + leaky;
// 1 = bf16 NCHW + leaky; 2 = fp32 NCHW + bias + fused depthwise(f2,ktr).
// ---------------------------------------------------------------------------
template <int OMODE>
__global__ __launch_bounds__(512, 2) void k_convG(
    const ushort_t* __restrict__ in, const ushort_t* __restrict__ zv,
    const ushort_t* __restrict__ wp, const float* __restrict__ bias,
    const ushort_t* __restrict__ f2, const float* __restrict__ ktr,
    void* __restrict__ outp) {
    extern __shared__ char smem_raw[];
    ushort_t* wlds = (ushort_t*)smem_raw;        // 36864 shorts (72 KB)
    ushort_t* xs = wlds + WSH;                   // 2 x 17152 shorts (68.6 KB)

    const int tid = threadIdx.x;
    const int lane = tid & 63;
    const int wv = tid >> 6;                     // 0..7
    const unsigned bid = blockIdx.x;
    const unsigned L = (bid & 7u) * 256u + (bid >> 3);  // 2048 = 8*256 bijective
    const int h0 = (L & 127) * 2, b = L >> 7;
    const int l31 = lane & 31, lhi = lane >> 5;
    const int pw0 = (wv & 3) * 64;               // pixel band
    const int rbase = wv >> 2;                   // 0 or 1
    const int ro = h0 + rbase;                   // this wave's output row

    const ushort_t* rb0 = (h0 > 0)    ? in + ((size_t)(b * 256 + h0 - 1)) * 16384 : zv;
    const ushort_t* rb1 =               in + ((size_t)(b * 256 + h0)) * 16384;
    const ushort_t* rb2 =               in + ((size_t)(b * 256 + h0 + 1)) * 16384;
    const ushort_t* rb3 = (h0 < 254)  ? in + ((size_t)(b * 256 + h0 + 2)) * 16384 : zv;

    f32x16 acc[2][2];
#pragma unroll
    for (int a = 0; a < 2; ++a)
#pragma unroll
        for (int c = 0; c < 2; ++c) acc[a][c] = (f32x16)0.0f;

    // Prologue: weights (9 loads/wave, linear) + stage chunk0/chunk1.
#pragma unroll
    for (int i = 0; i < 9; ++i) {
        int idx = wv * 9 + i;  // 0..71, exact
        gload_lds16(wp + (size_t)idx * 512 + lane * 8, wlds + (size_t)idx * 512);
    }
    STAGE4(0, 0);
    STAGE4(1, BSH);
    VMCNT(5);  // retire weights + S0; keep S1 in flight
    RBAR(); SCHED0();
    computeG(wlds, xs, 0, 0, lane, pw0, l31, lhi, rbase, acc);
    RBAR();                       // all waves done reading buf0
    STAGE4(2, 0);
    VMCNT(5);                     // retire S1; keep S2
    RBAR(); SCHED0();
    computeG(wlds, xs, BSH, 1, lane, pw0, l31, lhi, rbase, acc);
    RBAR();
    STAGE4(3, BSH);
    VMCNT(5);                     // retire S2; keep S3
    RBAR(); SCHED0();
    computeG(wlds, xs, 0, 2, lane, pw0, l31, lhi, rbase, acc);
    VMCNT(0);                     // S3 resident (epilogue of pipeline)
    RBAR(); SCHED0();
    computeG(wlds, xs, BSH, 3, lane, pw0, l31, lhi, rbase, acc);

    // Epilogues. D layout: col(pix)=lane&31, row(co)=(reg&3)+8*(reg>>2)+4*(lane>>5)
    const int co_b = 4 * lhi;
    if (OMODE == 0) {
        // bf16 NHWC + leaky
        ushort_t* outb = (ushort_t*)outp + ((size_t)(b * 256 + ro)) * 16384;
#pragma unroll
        for (int ct = 0; ct < 2; ++ct)
#pragma unroll
            for (int pt = 0; pt < 2; ++pt) {
                int pix = pw0 + pt * 32 + l31;
                ushort_t* po = outb + (size_t)pix * 64 + ct * 32 + co_b;
#pragma unroll
                for (int q = 0; q < 4; ++q) {
                    float4v bv = *(const float4v*)(bias + ct * 32 + co_b + 8 * q);
                    short4v sv;
#pragma unroll
                    for (int m = 0; m < 4; ++m) {
                        float v = lrelu(acc[ct][pt][q * 4 + m] + bv[m]);
                        sv[m] = (short)f2bf(v);
                    }
                    *(short4v*)(po + 8 * q) = sv;
                }
            }
    } else if (OMODE == 1) {
        // bf16 NCHW + leaky
        ushort_t* pb = (ushort_t*)outp + (((size_t)b * 64) << 16) + ro * 256;
#pragma unroll
        for (int ct = 0; ct < 2; ++ct)
#pragma unroll
            for (int pt = 0; pt < 2; ++pt) {
                int pix = pw0 + pt * 32 + l31;
#pragma unroll
                for (int q = 0; q < 4; ++q) {
                    float4v bv = *(const float4v*)(bias + ct * 32 + co_b + 8 * q);
#pragma unroll
                    for (int m = 0; m < 4; ++m) {
                        int c = ct * 32 + co_b + 8 * q + m;
                        float v = lrelu(acc[ct][pt][q * 4 + m] + bv[m]);
                        pb[((size_t)c << 16) + pix] = f2bf(v);
                    }
                }
            }
    } else {
        // fp32 NCHW final: out = conv + bias + depthwise(f2, ktr)  (mv in ktr)
        float* pb = (float*)outp + (((size_t)b * 64) << 16) + ro * 256;
#pragma unroll
        for (int ct = 0; ct < 2; ++ct)
#pragma unroll
            for (int pt = 0; pt < 2; ++pt) {
                int pix = pw0 + pt * 32 + l31;
#pragma unroll
                for (int q = 0; q < 4; ++q) {
                    const int cb4 = ct * 32 + co_b + 8 * q;
                    float4v kv[9];
#pragma unroll
                    for (int t9 = 0; t9 < 9; ++t9)
                        kv[t9] = *(const float4v*)(ktr + b * 576 + t9 * 64 + cb4);
                    float4v bv = *(const float4v*)(bias + cb4);
                    float dw4[4] = {0.f, 0.f, 0.f, 0.f};
#pragma unroll
                    for (int m = 0; m < 4; ++m) {
                        const ushort_t* f2c =
                            f2 + (((size_t)(b * 64 + cb4 + m)) << 16);
#pragma unroll
                        for (int rr2 = 0; rr2 < 3; ++rr2) {
                            int hh = ro - 1 + rr2;
                            if ((unsigned)hh >= 256u) continue;  // wave-uniform
                            const ushort_t* fr = f2c + hh * 256;
#pragma unroll
                            for (int dx = 0; dx < 3; ++dx) {
                                int wsx = pix + dx - 1;
                                bool ok = (unsigned)wsx < 256u;
                                float xv = ok ? bf2f(fr[ok ? wsx : 0]) : 0.f;
                                dw4[m] = fmaf(kv[rr2 * 3 + dx][m], xv, dw4[m]);
                            }
                        }
                    }
#pragma unroll
                    for (int m = 0; m < 4; ++m) {
                        float v = acc[ct][pt][q * 4 + m] + bv[m] + dw4[m];
                        pb[((size_t)(cb4 + m) << 16) + pix] = v;
                    }
                }
            }
    }
}

// ---------------------------------------------------------------------------
extern "C" void kernel_launch(void* const* d_in, const int* in_sizes, int n_in,
                              void* d_out, int out_size, void* d_ws, size_t ws_size,
                              hipStream_t stream) {
    const float* x   = (const float*)d_in[0];
    const float* t   = (const float*)d_in[1];
    const float* tW1 = (const float*)d_in[2];
    const float* tW2 = (const float*)d_in[3];
    const float* fW1 = (const float*)d_in[4];
    const float* fb1 = (const float*)d_in[5];
    const float* fW2 = (const float*)d_in[6];
    const float* fb2 = (const float*)d_in[7];
    const float* kW1 = (const float*)d_in[8];
    const float* kW2 = (const float*)d_in[9];
    const float* cW  = (const float*)d_in[10];
    const float* cb  = (const float*)d_in[11];

    // ws: [ktr 36K @0][wp 216K @65536][zv 32K @294912]
    //     [R1 xbf 128MB @512K][R2 f2 128MB @512K+128MB]
    // f1 (bf16 NHWC) lives in d_out[0..128MB) — dead before conv3dw overwrites.
    char* ws = (char*)d_ws;
    float*    ktr  = (float*)ws;
    ushort_t* wp   = (ushort_t*)(ws + 65536);
    ushort_t* zv   = (ushort_t*)(ws + 294912);
    ushort_t* xbf  = (ushort_t*)(ws + (512u << 10));
    ushort_t* f2n  = (ushort_t*)(ws + (512u << 10) + ((size_t)128 << 20));
    ushort_t* f1bf = (ushort_t*)d_out;
    float*    out  = (float*)d_out;

    // Allow >64KB dynamic LDS (142336 B) for the conv kernels.
    hipFuncSetAttribute(reinterpret_cast<const void*>(&k_convG<0>),
                        hipFuncAttributeMaxDynamicSharedMemorySize, DYN_LDS);
    hipFuncSetAttribute(reinterpret_cast<const void*>(&k_convG<1>),
                        hipFuncAttributeMaxDynamicSharedMemorySize, DYN_LDS);
    hipFuncSetAttribute(reinterpret_cast<const void*>(&k_convG<2>),
                        hipFuncAttributeMaxDynamicSharedMemorySize, DYN_LDS);

    k_tiny<<<dim3(16), dim3(64), 0, stream>>>(t, tW1, tW2, kW1, kW2, ktr);
    k_zrow<<<dim3(8), dim3(256), 0, stream>>>(zv);
    k_pack<<<dim3((3 * 36864 + 255) / 256), dim3(256), 0, stream>>>(fW1, fW2, cW, wp);
    k_tr<<<dim3(4096), dim3(256), 0, stream>>>(x, xbf);

    k_convG<0><<<dim3(2048), dim3(512), DYN_LDS, stream>>>(
        xbf, zv, wp, fb1, nullptr, nullptr, (void*)f1bf);
    k_convG<1><<<dim3(2048), dim3(512), DYN_LDS, stream>>>(
        f1bf, zv, wp + 36864, fb2, nullptr, nullptr, (void*)f2n);
    k_convG<2><<<dim3(2048), dim3(512), DYN_LDS, stream>>>(
        xbf, zv, wp + 2 * 36864, cb, f2n, ktr, (void*)out);
}

// Round 11
// 635.100 us; speedup vs baseline: 1.7058x; 1.7058x over previous
//
#include <hip/hip_runtime.h>
#include <cstdint>

// B=16, C=64, H=W=256. 3x3 convs via bf16 MFMA implicit GEMM.
// Round 11: depthwise de-fused again (k_fin restored; round-10's fused DW
// epilogue was the 740us disaster — scattered 2B NCHW reads). conv1+conv3
// re-merged on the weights-in-LDS structure: chunk-sliced double-buffered
// weight tiles (36 rows/chunk) + pixel tiles, uniform 10 loads/wave/chunk,
// counted vmcnt(10); compute cluster is pure-LDS (A and B via ds_read).
using short8  = __attribute__((ext_vector_type(8))) short;
using short4v = __attribute__((ext_vector_type(4))) short;
using f32x16  = __attribute__((ext_vector_type(16))) float;
using float4v = __attribute__((ext_vector_type(4))) float;
typedef unsigned short ushort_t;

#define CSLOTS 2080       // 4 rows x 520 slots per pixel chunk
#define BSLOTS 2144       // padded (stage stripes overrun to 2139)
#define XSH (BSLOTS * 8)  // pixel buf shorts = 17152
#define WROWS 40          // 36 used + 4 pad (8 waves x 5 rows)
#define WCH (WROWS * 512) // weight buf shorts = 20480
#define W1SH 36864        // full single-conv weight shorts (72 rows)
#define DYN13 ((2 * WCH + 2 * XSH) * 2)   // 150528 B
#define DYN2  ((W1SH + 2 * XSH) * 2)      // 142336 B

__device__ __forceinline__ float lrelu(float x) { return x > 0.f ? x : 0.1f * x; }

__device__ __forceinline__ ushort_t f2bf(float f) {
    union { float f; unsigned u; } v; v.f = f;
    unsigned r = (v.u + 0x7FFFu + ((v.u >> 16) & 1u)) >> 16;
    return (ushort_t)r;
}
__device__ __forceinline__ float bf2f(ushort_t b) {
    union { unsigned u; float f; } v; v.u = ((unsigned)b) << 16; return v.f;
}

// async 16B global -> LDS (dest = wave-uniform base; HW adds lane*16)
__device__ __forceinline__ void gload_lds16(const ushort_t* g, ushort_t* l) {
    __builtin_amdgcn_global_load_lds(
        (const __attribute__((address_space(1))) void*)g,
        (__attribute__((address_space(3))) void*)l, 16, 0, 0);
}

#define VMCNT(n) asm volatile("s_waitcnt vmcnt(" #n ")" ::: "memory")
#define RBAR() __builtin_amdgcn_s_barrier()
#define SCHED0() __builtin_amdgcn_sched_barrier(0)

// ---------------------------------------------------------------------------
// Tiny branch: ktr[b][tap][c] = leaky(kern) * sigmoid-gate (mv folded in).
// ---------------------------------------------------------------------------
__global__ void k_tiny(const float* __restrict__ t, const float* __restrict__ tW1,
                       const float* __restrict__ tW2, const float* __restrict__ kW1,
                       const float* __restrict__ kW2, float* __restrict__ ktr) {
    int b = blockIdx.x;
    int c = threadIdx.x;  // 64
    __shared__ float h1[64], g1[64];
    float ts = t[b];
    h1[c] = lrelu(ts * tW1[c]);
    g1[c] = lrelu(ts * kW1[c]);
    __syncthreads();
    float s = 0.f;
    for (int j = 0; j < 64; ++j) s = fmaf(tW2[c * 64 + j], h1[j], s);
    float mvv = 1.f / (1.f + expf(-s));
    for (int q = 0; q < 9; ++q) {
        float s2 = 0.f;
        for (int j = 0; j < 64; ++j) s2 = fmaf(kW2[(c * 9 + q) * 64 + j], g1[j], s2);
        ktr[b * 576 + q * 64 + c] = lrelu(s2) * mvv;
    }
}

// ---------------------------------------------------------------------------
// Zero row buffer (edge-redirect source for staging).
// ---------------------------------------------------------------------------
__global__ void k_zrow(ushort_t* __restrict__ z) {
    int i = blockIdx.x * 256 + threadIdx.x;  // 2048 threads, 16384 shorts
    *(short8*)(z + (size_t)i * 8) = (short8)0;
}

// ---------------------------------------------------------------------------
// Pack weights.
// wpM: [chunk][row 0..35][lane][8]  rows 0-17: fW1 (t*2+ct), 18-35: cW.
// wp2: [chunk][row 0..17][lane][8]  fW2.
//   element = W[co = ct*32+(lane&31)][ci = chunk*16+(lane>>5)*8+j][tap t]
// ---------------------------------------------------------------------------
__global__ void k_pack(const float* __restrict__ w1, const float* __restrict__ w2,
                       const float* __restrict__ w3, ushort_t* __restrict__ wpM,
                       ushort_t* __restrict__ wp2) {
    int idx = blockIdx.x * 256 + threadIdx.x;
    const int NM = 4 * 36 * 512;
    if (idx >= NM + 4 * 18 * 512) return;
    const float* W;
    ushort_t* dst;
    int chunk, row;
    int e;
    if (idx < NM) {
        chunk = idx / (36 * 512);
        int rem = idx % (36 * 512);
        row = rem / 512;
        e = rem % 512;
        W = (row < 18) ? w1 : w3;
        dst = wpM + idx;
        row %= 18;
    } else {
        int i2 = idx - NM;
        chunk = i2 / (18 * 512);
        int rem = i2 % (18 * 512);
        row = rem / 512;
        e = rem % 512;
        W = w2;
        dst = wp2 + i2;
    }
    int lane = e >> 3, j = e & 7;
    int t = row >> 1, ct = row & 1;
    int co = ct * 32 + (lane & 31);
    int ci = chunk * 16 + (lane >> 5) * 8 + j;
    *dst = f2bf(W[(co * 64 + ci) * 9 + t]);
}

// ---------------------------------------------------------------------------
// Transpose x: fp32 NCHW -> bf16 NHWC (width-256 rows). Block = (b,h).
// ---------------------------------------------------------------------------
__global__ __launch_bounds__(256) void k_tr(const float* __restrict__ x,
                                            ushort_t* __restrict__ xbf) {
    int bid = blockIdx.x;
    int h = bid & 255, b = bid >> 8;
    int t = threadIdx.x;
    for (int it = 0; it < 8; ++it) {
        int idx = t + it * 256;  // (w, g)
        int g = idx & 7, w = idx >> 3;
        const float* src = x + (((size_t)(b * 64 + g * 8) * 256 + h) * 256 + w);
        short8 v;
#pragma unroll
        for (int j = 0; j < 8; ++j) v[j] = (short)f2bf(src[(size_t)j * 65536]);
        *(short8*)(xbf + (((size_t)(b * 256 + h) * 256 + w) * 64 + g * 8)) = v;
    }
}

// ---------------------------------------------------------------------------
// Stage one 16-ci pixel chunk: 4 rows x 258 pix, 5 x gload_lds16 per wave.
// Inverse swizzle baked into per-lane source address.
// ---------------------------------------------------------------------------
#define STAGE_X(chunk, xbase)                                                    \
    {                                                                            \
        _Pragma("unroll")                                                        \
        for (int i_ = 0; i_ < 5; ++i_) {                                         \
            int base_ = wv * 260 + i_ * 64;                                      \
            int S_ = base_ + lane;                                               \
            S_ = S_ < CSLOTS ? S_ : CSLOTS - 1;                                  \
            int r_ = (S_ >= 1560) ? 3 : ((S_ >= 1040) ? 2 : ((S_ >= 520) ? 1 : 0)); \
            int rem_ = S_ - r_ * 520;                                            \
            int mg_ = rem_ >> 3, sl_ = rem_ & 7;                                 \
            int sp_ = sl_ ^ (mg_ & 7);                                           \
            int p_ = mg_ * 4 + (sp_ >> 1), g_ = sp_ & 1;                         \
            int wsx_ = p_ - 1;                                                   \
            bool edge_ = (unsigned)wsx_ >= 256u;                                 \
            const ushort_t* rp_ =                                                \
                (r_ == 0) ? rb0 : ((r_ == 1) ? rb1 : ((r_ == 2) ? rb2 : rb3));   \
            const ushort_t* src_ =                                               \
                edge_ ? zv : (rp_ + wsx_ * 64 + (chunk)*16 + g_ * 8);            \
            gload_lds16(src_, xs + (xbase) + (size_t)base_ * 8);                 \
        }                                                                        \
    }

// Stage one 36-row weight chunk slice: 5 x gload_lds16 per wave (rows 36-39
// are clamped-source dups into the pad rows; never read).
#define STAGE_W(chunk, wbase)                                                    \
    {                                                                            \
        _Pragma("unroll")                                                        \
        for (int i_ = 0; i_ < 5; ++i_) {                                         \
            int row_ = wv * 5 + i_;                                              \
            int rc_ = row_ > 35 ? 35 : row_;                                     \
            gload_lds16(wpM + (size_t)((chunk)*36 + rc_) * 512 + lane * 8,       \
                        wlds + (wbase) + (size_t)row_ * 512);                    \
        }                                                                        \
    }

// ---------------------------------------------------------------------------
// Merged conv1+conv3 compute: one B ds_read feeds 4 MFMAs. Pure LDS cluster.
// ---------------------------------------------------------------------------
__device__ __forceinline__ void computeM(const ushort_t* __restrict__ wlds,
                                         const ushort_t* __restrict__ xs,
                                         int wbase, int xbase, int lane, int pw0,
                                         int l31, int lhi, int rbase,
                                         f32x16 (&accA)[2][2], f32x16 (&accC)[2][2]) {
    __builtin_amdgcn_s_setprio(1);
#pragma unroll
    for (int t = 0; t < 9; ++t) {
        short8 a0 = *(const short8*)(wlds + wbase + (size_t)(t * 2 + 0) * 512 + lane * 8);
        short8 a1 = *(const short8*)(wlds + wbase + (size_t)(t * 2 + 1) * 512 + lane * 8);
        short8 c0 = *(const short8*)(wlds + wbase + (size_t)(18 + t * 2 + 0) * 512 + lane * 8);
        short8 c1 = *(const short8*)(wlds + wbase + (size_t)(18 + t * 2 + 1) * 512 + lane * 8);
        const int dwx = t % 3, rr = t / 3;
        const int rowIdx = rbase + rr;
#pragma unroll
        for (int pt = 0; pt < 2; ++pt) {
            int p = pw0 + pt * 32 + l31 + dwx;
            int mg = p >> 2;
            int sl = ((p & 3) * 2 + lhi) ^ (mg & 7);
            short8 bf = *(const short8*)(
                xs + xbase + (size_t)(rowIdx * 520 + mg * 8 + sl) * 8);
            accA[0][pt] = __builtin_amdgcn_mfma_f32_32x32x16_bf16(a0, bf, accA[0][pt], 0, 0, 0);
            accA[1][pt] = __builtin_amdgcn_mfma_f32_32x32x16_bf16(a1, bf, accA[1][pt], 0, 0, 0);
            accC[0][pt] = __builtin_amdgcn_mfma_f32_32x32x16_bf16(c0, bf, accC[0][pt], 0, 0, 0);
            accC[1][pt] = __builtin_amdgcn_mfma_f32_32x32x16_bf16(c1, bf, accC[1][pt], 0, 0, 0);
        }
    }
    __builtin_amdgcn_s_setprio(0);
}

// ---------------------------------------------------------------------------
// Merged conv1+conv3. Block = (b, h-pair) XCD-swizzled; 8 waves.
// accA: fW1+fb1+leaky -> f1 bf16 NHWC (ws R2). accC: cW+cb -> fp32 NCHW d_out.
// ---------------------------------------------------------------------------
__global__ __launch_bounds__(512, 2) void k_conv13M(
    const ushort_t* __restrict__ in, const ushort_t* __restrict__ zv,
    const ushort_t* __restrict__ wpM, const float* __restrict__ ba,
    const float* __restrict__ bc, ushort_t* __restrict__ f1out,
    float* __restrict__ cres) {
    extern __shared__ char smem_raw[];
    ushort_t* wlds = (ushort_t*)smem_raw;   // 2 x 20480 shorts
    ushort_t* xs = wlds + 2 * WCH;          // 2 x 17152 shorts

    const int tid = threadIdx.x;
    const int lane = tid & 63;
    const int wv = tid >> 6;
    const unsigned bid = blockIdx.x;
    const unsigned L = (bid & 7u) * 256u + (bid >> 3);  // 2048 = 8*256 bijective
    const int h0 = (L & 127) * 2, b = L >> 7;
    const int l31 = lane & 31, lhi = lane >> 5;
    const int pw0 = (wv & 3) * 64;
    const int rbase = wv >> 2;
    const int ro = h0 + rbase;

    const ushort_t* rb0 = (h0 > 0)   ? in + ((size_t)(b * 256 + h0 - 1)) * 16384 : zv;
    const ushort_t* rb1 =              in + ((size_t)(b * 256 + h0)) * 16384;
    const ushort_t* rb2 =              in + ((size_t)(b * 256 + h0 + 1)) * 16384;
    const ushort_t* rb3 = (h0 < 254) ? in + ((size_t)(b * 256 + h0 + 2)) * 16384 : zv;

    f32x16 accA[2][2], accC[2][2];
#pragma unroll
    for (int a = 0; a < 2; ++a)
#pragma unroll
        for (int c = 0; c < 2; ++c) { accA[a][c] = (f32x16)0.0f; accC[a][c] = (f32x16)0.0f; }

    STAGE_W(0, 0); STAGE_X(0, 0);
    STAGE_W(1, WCH); STAGE_X(1, XSH);
    VMCNT(10);  // chunk0 (W+X) resident; chunk1's 10 in flight
    RBAR(); SCHED0();
    computeM(wlds, xs, 0, 0, lane, pw0, l31, lhi, rbase, accA, accC);
    RBAR();
    STAGE_W(2, 0); STAGE_X(2, 0);
    VMCNT(10);  // chunk1 resident; chunk2 in flight
    RBAR(); SCHED0();
    computeM(wlds, xs, WCH, XSH, lane, pw0, l31, lhi, rbase, accA, accC);
    RBAR();
    STAGE_W(3, WCH); STAGE_X(3, XSH);
    VMCNT(10);  // chunk2 resident; chunk3 in flight
    RBAR(); SCHED0();
    computeM(wlds, xs, 0, 0, lane, pw0, l31, lhi, rbase, accA, accC);
    VMCNT(0);   // chunk3 resident
    RBAR(); SCHED0();
    computeM(wlds, xs, WCH, XSH, lane, pw0, l31, lhi, rbase, accA, accC);

    // Epilogues. D layout: col(pix)=lane&31, row(co)=(reg&3)+8*(reg>>2)+4*(lane>>5)
    const int co_b = 4 * lhi;
    {   // conv1 -> bf16 NHWC + leaky
        ushort_t* outb = f1out + ((size_t)(b * 256 + ro)) * 16384;
#pragma unroll
        for (int ct = 0; ct < 2; ++ct)
#pragma unroll
            for (int pt = 0; pt < 2; ++pt) {
                int pix = pw0 + pt * 32 + l31;
                ushort_t* po = outb + (size_t)pix * 64 + ct * 32 + co_b;
#pragma unroll
                for (int q = 0; q < 4; ++q) {
                    float4v bv = *(const float4v*)(ba + ct * 32 + co_b + 8 * q);
                    short4v sv;
#pragma unroll
                    for (int m = 0; m < 4; ++m) {
                        float v = lrelu(accA[ct][pt][q * 4 + m] + bv[m]);
                        sv[m] = (short)f2bf(v);
                    }
                    *(short4v*)(po + 8 * q) = sv;
                }
            }
    }
    {   // conv3 -> fp32 NCHW + cb
        float* pb = cres + (((size_t)b * 64) << 16) + ro * 256;
#pragma unroll
        for (int ct = 0; ct < 2; ++ct)
#pragma unroll
            for (int pt = 0; pt < 2; ++pt) {
                int pix = pw0 + pt * 32 + l31;
#pragma unroll
                for (int q = 0; q < 4; ++q) {
                    float4v bv = *(const float4v*)(bc + ct * 32 + co_b + 8 * q);
#pragma unroll
                    for (int m = 0; m < 4; ++m) {
                        int c = ct * 32 + co_b + 8 * q + m;
                        pb[((size_t)c << 16) + pix] = accC[ct][pt][q * 4 + m] + bv[m];
                    }
                }
            }
    }
}

// ---------------------------------------------------------------------------
// conv2: full weights in LDS (static slice), bf16 NHWC in -> leaky -> bf16
// NCHW out. Round-10 structure (proven).
// ---------------------------------------------------------------------------
__global__ __launch_bounds__(512, 2) void k_conv2(
    const ushort_t* __restrict__ in, const ushort_t* __restrict__ zv,
    const ushort_t* __restrict__ wp2, const float* __restrict__ bias,
    ushort_t* __restrict__ outp) {
    extern __shared__ char smem_raw[];
    ushort_t* wlds = (ushort_t*)smem_raw;   // 36864 shorts (72 rows: [chunk][18])
    ushort_t* xs = wlds + W1SH;             // 2 x 17152 shorts

    const int tid = threadIdx.x;
    const int lane = tid & 63;
    const int wv = tid >> 6;
    const unsigned bid = blockIdx.x;
    const unsigned L = (bid & 7u) * 256u + (bid >> 3);
    const int h0 = (L & 127) * 2, b = L >> 7;
    const int l31 = lane & 31, lhi = lane >> 5;
    const int pw0 = (wv & 3) * 64;
    const int rbase = wv >> 2;
    const int ro = h0 + rbase;

    const ushort_t* rb0 = (h0 > 0)   ? in + ((size_t)(b * 256 + h0 - 1)) * 16384 : zv;
    const ushort_t* rb1 =              in + ((size_t)(b * 256 + h0)) * 16384;
    const ushort_t* rb2 =              in + ((size_t)(b * 256 + h0 + 1)) * 16384;
    const ushort_t* rb3 = (h0 < 254) ? in + ((size_t)(b * 256 + h0 + 2)) * 16384 : zv;

    f32x16 acc[2][2];
#pragma unroll
    for (int a = 0; a < 2; ++a)
#pragma unroll
        for (int c = 0; c < 2; ++c) acc[a][c] = (f32x16)0.0f;

#define COMPUTE2(chunk, xbase)                                                      \
    {                                                                               \
        __builtin_amdgcn_s_setprio(1);                                              \
        _Pragma("unroll")                                                           \
        for (int t_ = 0; t_ < 9; ++t_) {                                            \
            short8 a0 = *(const short8*)(wlds + (size_t)((chunk)*18 + t_ * 2) * 512 + lane * 8); \
            short8 a1 = *(const short8*)(wlds + (size_t)((chunk)*18 + t_ * 2 + 1) * 512 + lane * 8); \
            const int dwx_ = t_ % 3, rr_ = t_ / 3;                                  \
            const int rowIdx_ = rbase + rr_;                                        \
            _Pragma("unroll")                                                       \
            for (int pt_ = 0; pt_ < 2; ++pt_) {                                     \
                int p_ = pw0 + pt_ * 32 + l31 + dwx_;                               \
                int mg_ = p_ >> 2;                                                  \
                int sl_ = ((p_ & 3) * 2 + lhi) ^ (mg_ & 7);                         \
                short8 bf = *(const short8*)(                                       \
                    xs + (xbase) + (size_t)(rowIdx_ * 520 + mg_ * 8 + sl_) * 8);    \
                acc[0][pt_] = __builtin_amdgcn_mfma_f32_32x32x16_bf16(a0, bf, acc[0][pt_], 0, 0, 0); \
                acc[1][pt_] = __builtin_amdgcn_mfma_f32_32x32x16_bf16(a1, bf, acc[1][pt_], 0, 0, 0); \
            }                                                                       \
        }                                                                           \
        __builtin_amdgcn_s_setprio(0);                                              \
    }

    // Prologue: full weights (9 loads/wave, linear) + chunk0/chunk1 pixels.
#pragma unroll
    for (int i = 0; i < 9; ++i) {
        int idx = wv * 9 + i;  // 0..71 exact
        gload_lds16(wp2 + (size_t)idx * 512 + lane * 8, wlds + (size_t)idx * 512);
    }
    STAGE_X(0, 0);
    STAGE_X(1, XSH);
    VMCNT(5);  // weights + X0 resident; X1 in flight
    RBAR(); SCHED0();
    COMPUTE2(0, 0);
    RBAR();
    STAGE_X(2, 0);
    VMCNT(5);
    RBAR(); SCHED0();
    COMPUTE2(1, XSH);
    RBAR();
    STAGE_X(3, XSH);
    VMCNT(5);
    RBAR(); SCHED0();
    COMPUTE2(2, 0);
    VMCNT(0);
    RBAR(); SCHED0();
    COMPUTE2(3, XSH);
#undef COMPUTE2

    const int co_b = 4 * lhi;
    // bf16 NCHW out
    ushort_t* pb = outp + (((size_t)b * 64) << 16) + ro * 256;
#pragma unroll
    for (int ct = 0; ct < 2; ++ct)
#pragma unroll
        for (int pt = 0; pt < 2; ++pt) {
            int pix = pw0 + pt * 32 + l31;
#pragma unroll
            for (int q = 0; q < 4; ++q) {
                float4v bv = *(const float4v*)(bias + ct * 32 + co_b + 8 * q);
#pragma unroll
                for (int m = 0; m < 4; ++m) {
                    int c = ct * 32 + co_b + 8 * q + m;
                    float v = lrelu(acc[ct][pt][q * 4 + m] + bv[m]);
                    pb[((size_t)c << 16) + pix] = f2bf(v);
                }
            }
        }
}

// ---------------------------------------------------------------------------
// Final depthwise: out[b][c][h][w] += sum_tap ktr[b][tap][c] * f2[b][c][h'][w']
// Block = (b, c, 8-row band); f2 is bf16 NCHW. High occupancy.
// ---------------------------------------------------------------------------
__global__ __launch_bounds__(256) void k_fin(const ushort_t* __restrict__ f2,
                                             const float* __restrict__ ktr,
                                             float* __restrict__ out) {
    __shared__ __align__(16) ushort_t s[10 * 272];
    const unsigned bid = blockIdx.x;
    const unsigned L = (bid & 7u) * 4096u + (bid >> 3);  // bijective, 32768=8*4096
    const int hb = L & 31, c = (L >> 5) & 63, b = L >> 11;
    const int h0 = hb * 8;
    const int w = threadIdx.x;

    const ushort_t* f2c = f2 + (((size_t)(b * 64 + c)) << 16);
    for (int i = w; i < 320; i += 256) {
        int r = i >> 5, seg = i & 31;
        int hs = h0 - 1 + r;
        short8 v = (short8)0;
        if ((unsigned)hs < 256u) v = *(const short8*)(f2c + hs * 256 + seg * 8);
        *(short8*)(&s[r * 272 + 8 + seg * 8]) = v;
        if (seg == 0) s[r * 272 + 7] = 0;
        if (seg == 31) s[r * 272 + 264] = 0;
    }
    __syncthreads();

    float kv[9];
#pragma unroll
    for (int t9 = 0; t9 < 9; ++t9) kv[t9] = ktr[b * 576 + t9 * 64 + c];

    float lv[10], cv[10], rv[10];
#pragma unroll
    for (int r = 0; r < 10; ++r) {
        lv[r] = bf2f(s[r * 272 + 7 + w]);
        cv[r] = bf2f(s[r * 272 + 8 + w]);
        rv[r] = bf2f(s[r * 272 + 9 + w]);
    }

    float* ob = out + (((size_t)(b * 64 + c)) << 16) + h0 * 256 + w;
#pragma unroll
    for (int rr = 0; rr < 8; ++rr) {
        float dwv = 0.f;
#pragma unroll
        for (int r3 = 0; r3 < 3; ++r3) {
            dwv = fmaf(kv[r3 * 3 + 0], lv[rr + r3], dwv);
            dwv = fmaf(kv[r3 * 3 + 1], cv[rr + r3], dwv);
            dwv = fmaf(kv[r3 * 3 + 2], rv[rr + r3], dwv);
        }
        float* po = ob + rr * 256;
        *po = *po + dwv;
    }
}

// ---------------------------------------------------------------------------
extern "C" void kernel_launch(void* const* d_in, const int* in_sizes, int n_in,
                              void* d_out, int out_size, void* d_ws, size_t ws_size,
                              hipStream_t stream) {
    const float* x   = (const float*)d_in[0];
    const float* t   = (const float*)d_in[1];
    const float* tW1 = (const float*)d_in[2];
    const float* tW2 = (const float*)d_in[3];
    const float* fW1 = (const float*)d_in[4];
    const float* fb1 = (const float*)d_in[5];
    const float* fW2 = (const float*)d_in[6];
    const float* fb2 = (const float*)d_in[7];
    const float* kW1 = (const float*)d_in[8];
    const float* kW2 = (const float*)d_in[9];
    const float* cW  = (const float*)d_in[10];
    const float* cb  = (const float*)d_in[11];

    // ws: [ktr 36K @0][wpM 144K+wp2 72K @65536][zv 32K @294912]
    //     [R1 xbf->f2 128MB @512K][R2 f1 128MB @512K+128MB]
    char* ws = (char*)d_ws;
    float*    ktr  = (float*)ws;
    ushort_t* wpM  = (ushort_t*)(ws + 65536);
    ushort_t* wp2  = wpM + 4 * 36 * 512;
    ushort_t* zv   = (ushort_t*)(ws + 294912);
    ushort_t* xbf  = (ushort_t*)(ws + (512u << 10));                       // R1
    ushort_t* f1bf = (ushort_t*)(ws + (512u << 10) + ((size_t)128 << 20)); // R2
    ushort_t* f2n  = xbf;  // R1 reused: xbf dead after k_conv13M
    float*    out  = (float*)d_out;

    hipFuncSetAttribute(reinterpret_cast<const void*>(&k_conv13M),
                        hipFuncAttributeMaxDynamicSharedMemorySize, DYN13);
    hipFuncSetAttribute(reinterpret_cast<const void*>(&k_conv2),
                        hipFuncAttributeMaxDynamicSharedMemorySize, DYN2);

    k_tiny<<<dim3(16), dim3(64), 0, stream>>>(t, tW1, tW2, kW1, kW2, ktr);
    k_zrow<<<dim3(8), dim3(256), 0, stream>>>(zv);
    k_pack<<<dim3((4 * 36 * 512 + 4 * 18 * 512 + 255) / 256), dim3(256), 0, stream>>>(
        fW1, fW2, cW, wpM, wp2);
    k_tr<<<dim3(4096), dim3(256), 0, stream>>>(x, xbf);

    k_conv13M<<<dim3(2048), dim3(512), DYN13, stream>>>(
        xbf, zv, wpM, fb1, cb, f1bf, out);
    k_conv2<<<dim3(2048), dim3(512), DYN2, stream>>>(f1bf, zv, wp2, fb2, f2n);
    k_fin<<<dim3(32768), dim3(256), 0, stream>>>(f2n, ktr, out);
}